// Round 1
// baseline (231.472 us; speedup 1.0000x reference)
//
#include <hip/hip_runtime.h>

#define DNUM 1024
#define HIDN 128
#define NTOT 32768
#define MR 32
#define BKC 64

// workspace float offsets
#define T_OFF 0
#define P0_OFF 1024
#define S_OFF 1152
#define AGG_OFF 1216
#define GATE_OFF 2240
#define U1_OFF 3264
#define W2_FOFF 4288   // bf16 W2 copy starts here (byte offset 17152, 16B aligned)

typedef __attribute__((ext_vector_type(8))) short short8;
typedef __attribute__((ext_vector_type(4))) float f32x4;

__device__ __forceinline__ unsigned short f2bf(float x) {
  unsigned int u = __builtin_bit_cast(unsigned int, x);
  u = u + 0x7fffu + ((u >> 16) & 1u);   // round-to-nearest-even
  return (unsigned short)(u >> 16);
}
__device__ __forceinline__ float bf2f(unsigned int bits16) {
  unsigned int u = bits16 << 16;
  return __builtin_bit_cast(float, u);
}

// Kernel A: target row t = features[0] + pos_emb[dep0]; zero s/agg accumulators.
__global__ __launch_bounds__(256) void ka(const float* __restrict__ features,
                                          const int* __restrict__ depths,
                                          const float* __restrict__ pos_emb,
                                          float* __restrict__ ws) {
  int t = threadIdx.x;
  int dep = depths[0];
  dep = dep < 0 ? 0 : (dep > 31 ? 31 : dep);
  float4 fv = *(const float4*)(features + t * 4);
  float4 pe = *(const float4*)(pos_emb + dep * DNUM + t * 4);
  float4 r;
  r.x = fv.x + pe.x; r.y = fv.y + pe.y; r.z = fv.z + pe.z; r.w = fv.w + pe.w;
  *(float4*)(ws + T_OFF + t * 4) = r;
  float4 z = make_float4(0.f, 0.f, 0.f, 0.f);
  *(float4*)(ws + AGG_OFF + t * 4) = z;
  if (t < 64) ws[S_OFF + t] = 0.f;
}

// Kernel AW: block 0 -> partial0[j] = ab1[j] + t . aW1[j, 0:1024];
// blocks 1..128 -> convert aW1[:, 1024:2048] to bf16 into ws.
__global__ __launch_bounds__(256) void kaw(const float* __restrict__ aW1,
                                           const float* __restrict__ ab1,
                                           float* __restrict__ ws,
                                           unsigned short* __restrict__ w2) {
  int t = threadIdx.x, bid = blockIdx.x;
  if (bid == 0) {
    if (t < HIDN) {
      const float* wrow = aW1 + (size_t)t * (2 * DNUM);
      float p = ab1[t];
      for (int k = 0; k < DNUM; ++k) p += ws[T_OFF + k] * wrow[k];
      ws[P0_OFF + t] = p;
    }
    return;
  }
  int idx = ((bid - 1) * 256 + t) * 4;
  int j = idx >> 10, k = idx & 1023;
  float4 v = *(const float4*)(aW1 + (size_t)j * 2048 + 1024 + k);
  uint2 pk;
  pk.x = (unsigned int)f2bf(v.x) | ((unsigned int)f2bf(v.y) << 16);
  pk.y = (unsigned int)f2bf(v.z) | ((unsigned int)f2bf(v.w) << 16);
  *(uint2*)(w2 + idx) = pk;
}

// Kernel B (hot): per block, 32 path rows. Stream f to d_out, bf16 copy in LDS,
// MFMA GEMM vs W2 (staged per 64-k chunk), sigmoid scores, raw*f row-sum.
__global__ __launch_bounds__(256) void kbig(
    const float* __restrict__ features, const int* __restrict__ depths,
    const float* __restrict__ pos_emb, const float* __restrict__ p0,
    const float* __restrict__ aW2, const float* __restrict__ ab2,
    const unsigned short* __restrict__ w2, float* __restrict__ out,
    float* __restrict__ agg, float* __restrict__ sacc) {
  __shared__ __align__(16) unsigned char ldsA[MR * 2048];  // 64 KiB: 32 rows x 1024 bf16 (swizzled)
  __shared__ __align__(16) unsigned char scr[16384];       // 16 KiB: deps / B tile / partials
  const int t = threadIdx.x;
  const int bid = blockIdx.x;
  const int lane = t & 63;
  const int w = t >> 6;
  const int llo = lane & 15;
  const int lhi = lane >> 4;

  int* depsL = (int*)scr;
  if (t < MR) {
    int fr = 1 + bid * MR + t;
    int dp = (fr < NTOT) ? depths[fr] : 0;
    dp = dp < 0 ? 0 : (dp > 31 ? 31 : dp);
    depsL[t] = dp;
  }
  __syncthreads();

  // Phase 1: build f rows, write f32 to out, stage bf16 to LDS (XOR swizzle).
  const int col = t * 4;
  for (int i = 0; i < MR; ++i) {
    int fr = 1 + bid * MR + i;
    float4 f = make_float4(0.f, 0.f, 0.f, 0.f);
    if (fr < NTOT) {
      float4 fv = *(const float4*)(features + (size_t)fr * DNUM + col);
      float4 pe = *(const float4*)(pos_emb + depsL[i] * DNUM + col);
      f.x = fv.x + pe.x; f.y = fv.y + pe.y; f.z = fv.z + pe.z; f.w = fv.w + pe.w;
      *(float4*)(out + (size_t)fr * DNUM + col) = f;
    }
    uint2 pk;
    pk.x = (unsigned int)f2bf(f.x) | ((unsigned int)f2bf(f.y) << 16);
    pk.y = (unsigned int)f2bf(f.z) | ((unsigned int)f2bf(f.w) << 16);
    int off = (i * 2048 + t * 8) ^ ((i & 7) << 4);
    *(uint2*)(ldsA + off) = pk;
  }
  __syncthreads();

  // GEMM: acc[m][n] covers rows [m*16, m*16+16) x cols [w*32+n*16, ...+16)
  f32x4 acc[2][2];
#pragma unroll
  for (int m = 0; m < 2; ++m)
#pragma unroll
    for (int n = 0; n < 2; ++n) acc[m][n] = (f32x4){0.f, 0.f, 0.f, 0.f};

  for (int kc = 0; kc < DNUM / BKC; ++kc) {
    // Stage B chunk [128 j][64 k] bf16 (row-major by j, swizzled), 16 KiB.
#pragma unroll
    for (int u = 0; u < 4; ++u) {
      int unit = u * 256 + t;  // 1024 16-byte units
      int j = unit >> 3;
      int ku = unit & 7;
      uint4 v = *(const uint4*)(w2 + (size_t)j * DNUM + kc * BKC + ku * 8);
      int off = (j * 128 + ku * 16) ^ ((j & 7) << 4);
      *(uint4*)(scr + off) = v;
    }
    __syncthreads();
#pragma unroll
    for (int kk = 0; kk < 2; ++kk) {
      short8 av[2], bv[2];
#pragma unroll
      for (int m = 0; m < 2; ++m) {
        int row = m * 16 + llo;
        int off = (row * 2048 + (kc * BKC + kk * 32 + lhi * 8) * 2) ^ ((row & 7) << 4);
        av[m] = *(short8*)(ldsA + off);
      }
#pragma unroll
      for (int n = 0; n < 2; ++n) {
        int j = w * 32 + n * 16 + llo;
        int off = (j * 128 + (kk * 32 + lhi * 8) * 2) ^ ((j & 7) << 4);
        bv[n] = *(short8*)(scr + off);
      }
#pragma unroll
      for (int m = 0; m < 2; ++m)
#pragma unroll
        for (int n = 0; n < 2; ++n)
          acc[m][n] = __builtin_amdgcn_mfma_f32_16x16x32_bf16(av[m], bv[n], acc[m][n], 0, 0, 0);
    }
    __syncthreads();
  }

  // Epilogue 1: per-lane relu(h)+dot with aW2, reduce over the 16-lane col group.
  float p0v[2], wv[2];
#pragma unroll
  for (int n = 0; n < 2; ++n) {
    int j = w * 32 + n * 16 + llo;
    p0v[n] = p0[j];
    wv[n] = aW2[j];
  }
  float psum[2][4];
#pragma unroll
  for (int m = 0; m < 2; ++m)
#pragma unroll
    for (int e = 0; e < 4; ++e) {
      float s = 0.f;
#pragma unroll
      for (int n = 0; n < 2; ++n) {
        float h = acc[m][n][e] + p0v[n];
        h = fmaxf(h, 0.f);
        s += h * wv[n];
      }
      s += __shfl_xor(s, 1);
      s += __shfl_xor(s, 2);
      s += __shfl_xor(s, 4);
      s += __shfl_xor(s, 8);
      psum[m][e] = s;
    }
  float* part = (float*)scr;  // B tile done; reuse scratch
  if (llo == 0) {
#pragma unroll
    for (int m = 0; m < 2; ++m)
#pragma unroll
      for (int e = 0; e < 4; ++e) part[w * 32 + m * 16 + lhi * 4 + e] = psum[m][e];
  }
  __syncthreads();
  // Epilogue 2: combine 4 wave partials, sigmoid, mask padded row.
  if (t < MR) {
    float pre = part[t] + part[32 + t] + part[64 + t] + part[96 + t] + ab2[0];
    int fr = 1 + bid * MR + t;
    float raw = 0.f;
    if (fr < NTOT) raw = 1.f / (1.f + __expf(-pre));
    part[128 + t] = raw;
  }
  __syncthreads();
  // Epilogue 3: aggsum[col] += sum_rows raw * f (f from LDS bf16), s partial.
  float a0 = 0.f, a1 = 0.f, a2 = 0.f, a3 = 0.f;
  for (int lr = 0; lr < MR; ++lr) {
    float r = part[128 + lr];
    int off = (lr * 2048 + t * 8) ^ ((lr & 7) << 4);
    uint2 pk = *(uint2*)(ldsA + off);
    a0 += r * bf2f(pk.x & 0xffffu);
    a1 += r * bf2f(pk.x >> 16);
    a2 += r * bf2f(pk.y & 0xffffu);
    a3 += r * bf2f(pk.y >> 16);
  }
  atomicAdd(agg + col + 0, a0);
  atomicAdd(agg + col + 1, a1);
  atomicAdd(agg + col + 2, a2);
  atomicAdd(agg + col + 3, a3);
  if (t == 0) {
    float s = 0.f;
    for (int lr = 0; lr < MR; ++lr) s += part[128 + lr];
    atomicAdd(sacc + (bid & 63), s);
  }
}

// Kernel C1: c2 = [t, agg/s]; gate = sigmoid(gW.c2 + gb), u1 = relu(uW1.c2 + ub1).
__global__ __launch_bounds__(256) void kc1(const float* __restrict__ gW,
                                           const float* __restrict__ gb,
                                           const float* __restrict__ uW1,
                                           const float* __restrict__ ub1,
                                           float* __restrict__ ws) {
  __shared__ float c2[2048];
  __shared__ float sinv_sh;
  int t = threadIdx.x, bid = blockIdx.x;
  if (t == 0) {
    float s = 0.f;
    for (int i = 0; i < 64; ++i) s += ws[S_OFF + i];
    sinv_sh = (s > 0.f) ? 1.f / s : 1.f;
  }
  __syncthreads();
  float sinv = sinv_sh;
  for (int i = t; i < 2048; i += 256)
    c2[i] = (i < 1024) ? ws[T_OFF + i] : ws[AGG_OFF + i - 1024] * sinv;
  __syncthreads();
  int w = t >> 6, lane = t & 63;
  int isGate = bid < 256;
  int o = (isGate ? bid : bid - 256) * 4 + w;
  const float* W = isGate ? gW : uW1;
  float p = 0.f;
  for (int i = lane; i < 2048; i += 64) p += W[(size_t)o * 2048 + i] * c2[i];
  p += __shfl_xor(p, 1);
  p += __shfl_xor(p, 2);
  p += __shfl_xor(p, 4);
  p += __shfl_xor(p, 8);
  p += __shfl_xor(p, 16);
  p += __shfl_xor(p, 32);
  if (lane == 0) {
    float v = p + (isGate ? gb[o] : ub1[o]);
    v = isGate ? (1.f / (1.f + expf(-v))) : fmaxf(v, 0.f);
    ws[(isGate ? GATE_OFF : U1_OFF) + o] = v;
  }
}

// Kernel C2: upd = uW2.u1 + ub2; out[0] = t + gate * upd.
__global__ __launch_bounds__(256) void kc2(const float* __restrict__ uW2,
                                           const float* __restrict__ ub2,
                                           const float* __restrict__ ws,
                                           float* __restrict__ out) {
  __shared__ float u1[1024];
  int t = threadIdx.x, bid = blockIdx.x;
  for (int i = t; i < 1024; i += 256) u1[i] = ws[U1_OFF + i];
  __syncthreads();
  int w = t >> 6, lane = t & 63;
  int o = bid * 4 + w;
  float p = 0.f;
  for (int i = lane; i < 1024; i += 64) p += uW2[(size_t)o * 1024 + i] * u1[i];
  p += __shfl_xor(p, 1);
  p += __shfl_xor(p, 2);
  p += __shfl_xor(p, 4);
  p += __shfl_xor(p, 8);
  p += __shfl_xor(p, 16);
  p += __shfl_xor(p, 32);
  if (lane == 0) {
    float upd = p + ub2[o];
    out[o] = ws[T_OFF + o] + ws[GATE_OFF + o] * upd;
  }
}

extern "C" void kernel_launch(void* const* d_in, const int* in_sizes, int n_in,
                              void* d_out, int out_size, void* d_ws, size_t ws_size,
                              hipStream_t stream) {
  const float* features = (const float*)d_in[0];
  const int* depths = (const int*)d_in[1];
  const float* pos_emb = (const float*)d_in[2];
  const float* aW1 = (const float*)d_in[3];
  const float* ab1 = (const float*)d_in[4];
  const float* aW2 = (const float*)d_in[5];
  const float* ab2 = (const float*)d_in[6];
  const float* uW1 = (const float*)d_in[7];
  const float* ub1 = (const float*)d_in[8];
  const float* uW2 = (const float*)d_in[9];
  const float* ub2 = (const float*)d_in[10];
  const float* gW = (const float*)d_in[11];
  const float* gb = (const float*)d_in[12];
  float* out = (float*)d_out;
  float* ws = (float*)d_ws;
  unsigned short* w2 = (unsigned short*)(ws + W2_FOFF);

  hipLaunchKernelGGL(ka, dim3(1), dim3(256), 0, stream, features, depths, pos_emb, ws);
  hipLaunchKernelGGL(kaw, dim3(129), dim3(256), 0, stream, aW1, ab1, ws, w2);
  hipLaunchKernelGGL(kbig, dim3(1024), dim3(256), 0, stream, features, depths, pos_emb,
                     ws + P0_OFF, aW2, ab2, w2, out, ws + AGG_OFF, ws + S_OFF);
  hipLaunchKernelGGL(kc1, dim3(512), dim3(256), 0, stream, gW, gb, uW1, ub1, ws);
  hipLaunchKernelGGL(kc2, dim3(256), dim3(256), 0, stream, uW2, ub2, ws, out);
}

// Round 3
// 218.966 us; speedup vs baseline: 1.0571x; 1.0571x over previous
//
#include <hip/hip_runtime.h>

#define DNUM 1024
#define HIDN 128
#define NTOT 32768
#define MR 32

// workspace float offsets
#define T_OFF 0
#define P0_OFF 1024
#define S_OFF 1152
#define AGG_OFF 1216
#define GATE_OFF 2240
#define U1_OFF 3264
#define W2_FOFF 4288   // bf16 W2 copy starts here (byte offset 17152, 16B aligned)

typedef __attribute__((ext_vector_type(8))) short short8;
typedef __attribute__((ext_vector_type(4))) float f32x4;

__device__ __forceinline__ unsigned short f2bf(float x) {
  unsigned int u = __builtin_bit_cast(unsigned int, x);
  u = u + 0x7fffu + ((u >> 16) & 1u);   // round-to-nearest-even
  return (unsigned short)(u >> 16);
}
__device__ __forceinline__ float bf2f(unsigned int bits16) {
  unsigned int u = bits16 << 16;
  return __builtin_bit_cast(float, u);
}

// Kernel A: target row t = features[0] + pos_emb[dep0]; zero s/agg accumulators.
__global__ __launch_bounds__(256) void ka(const float* __restrict__ features,
                                          const int* __restrict__ depths,
                                          const float* __restrict__ pos_emb,
                                          float* __restrict__ ws) {
  int t = threadIdx.x;
  int dep = depths[0];
  dep = dep < 0 ? 0 : (dep > 31 ? 31 : dep);
  float4 fv = *(const float4*)(features + t * 4);
  float4 pe = *(const float4*)(pos_emb + dep * DNUM + t * 4);
  float4 r;
  r.x = fv.x + pe.x; r.y = fv.y + pe.y; r.z = fv.z + pe.z; r.w = fv.w + pe.w;
  *(float4*)(ws + T_OFF + t * 4) = r;
  float4 z = make_float4(0.f, 0.f, 0.f, 0.f);
  *(float4*)(ws + AGG_OFF + t * 4) = z;
  if (t < 64) ws[S_OFF + t] = 0.f;
}

// Kernel AW: block 0 -> partial0[j] = ab1[j] + t . aW1[j, 0:1024] (2 thr/output);
// blocks 1..128 -> convert aW1[:, 1024:2048] to bf16 into ws.
__global__ __launch_bounds__(256) void kaw(const float* __restrict__ aW1,
                                           const float* __restrict__ ab1,
                                           float* __restrict__ ws,
                                           unsigned short* __restrict__ w2) {
  int t = threadIdx.x, bid = blockIdx.x;
  if (bid == 0) {
    __shared__ float ph[256];
    int j = t >> 1, h = t & 1;
    const float* wrow = aW1 + (size_t)j * (2 * DNUM) + h * 512;
    const float* tr = ws + T_OFF + h * 512;
    float p = 0.f;
    for (int k = 0; k < 512; k += 4) {
      float4 wv = *(const float4*)(wrow + k);
      float4 tv = *(const float4*)(tr + k);
      p += wv.x * tv.x + wv.y * tv.y + wv.z * tv.z + wv.w * tv.w;
    }
    ph[t] = p;
    __syncthreads();
    if (t < HIDN) ws[P0_OFF + t] = ab1[t] + ph[t * 2] + ph[t * 2 + 1];
    return;
  }
  int idx = ((bid - 1) * 256 + t) * 4;
  int j = idx >> 10, k = idx & 1023;
  float4 v = *(const float4*)(aW1 + (size_t)j * 2048 + 1024 + k);
  uint2 pk;
  pk.x = (unsigned int)f2bf(v.x) | ((unsigned int)f2bf(v.y) << 16);
  pk.y = (unsigned int)f2bf(v.z) | ((unsigned int)f2bf(v.w) << 16);
  *(uint2*)(w2 + idx) = pk;
}

// Kernel B (hot): per block, 32 path rows, 512 threads (8 waves).
// Stream f to d_out (NT stores), bf16 copy in LDS, MFMA GEMM with B fragments
// read directly from L2-resident w2 (no barriers), sigmoid scores, raw*f sum.
__global__ __launch_bounds__(512, 4) void kbig(
    const float* __restrict__ features, const int* __restrict__ depths,
    const float* __restrict__ pos_emb, const float* __restrict__ p0,
    const float* __restrict__ aW2, const float* __restrict__ ab2,
    const unsigned short* __restrict__ w2, float* __restrict__ out,
    float* __restrict__ agg, float* __restrict__ sacc) {
  __shared__ __align__(16) unsigned char ldsA[MR * 2048];  // 64 KiB: 32 rows x 1024 bf16 (swizzled)
  __shared__ int depsL[MR];
  __shared__ float part[160];       // [0..127] wave partials, [128..159] raw
  __shared__ float comb[1024];      // epilogue half-combine
  const int t = threadIdx.x;
  const int bid = blockIdx.x;
  const int lane = t & 63;
  const int w = t >> 6;
  const int llo = lane & 15;
  const int lhi = lane >> 4;
  const int tc = t & 255;           // column thread
  const int th = t >> 8;            // row half
  const int col = tc * 4;

  if (t < MR) {
    int fr = 1 + bid * MR + t;
    int dp = (fr < NTOT) ? depths[fr] : 0;
    dp = dp < 0 ? 0 : (dp > 31 ? 31 : dp);
    depsL[t] = dp;
  }
  __syncthreads();

  // Phase 1: build f rows, NT-write f32 to out, stage bf16 to LDS (XOR swizzle).
  for (int ii = 0; ii < 16; ++ii) {
    int i = ii * 2 + th;
    int fr = 1 + bid * MR + i;
    float4 f = make_float4(0.f, 0.f, 0.f, 0.f);
    if (fr < NTOT) {
      float4 fv = *(const float4*)(features + (size_t)fr * DNUM + col);
      float4 pe = *(const float4*)(pos_emb + depsL[i] * DNUM + col);
      f.x = fv.x + pe.x; f.y = fv.y + pe.y; f.z = fv.z + pe.z; f.w = fv.w + pe.w;
      f32x4 fe = {f.x, f.y, f.z, f.w};
      __builtin_nontemporal_store(fe, (f32x4*)(out + (size_t)fr * DNUM + col));
    }
    uint2 pk;
    pk.x = (unsigned int)f2bf(f.x) | ((unsigned int)f2bf(f.y) << 16);
    pk.y = (unsigned int)f2bf(f.z) | ((unsigned int)f2bf(f.w) << 16);
    int off = (i * 2048 + tc * 8) ^ ((i & 7) << 4);
    *(uint2*)(ldsA + off) = pk;
  }
  __syncthreads();

  // GEMM: wave (wm,wn) -> rows [wm*16,+16) x cols [wn*32,+32). No barriers;
  // B fragments come straight from L2-resident w2.
  const int wm = w >> 2, wn = w & 3;
  f32x4 acc[2];
  acc[0] = (f32x4){0.f, 0.f, 0.f, 0.f};
  acc[1] = (f32x4){0.f, 0.f, 0.f, 0.f};
  const int arow = wm * 16 + llo;
  const int abase = arow * 2048;
  const int aswz = (arow & 7) << 4;
  const unsigned short* bpA = w2 + (size_t)(wn * 32 + llo) * DNUM + lhi * 8;
  const unsigned short* bpB = bpA + 16 * DNUM;

#pragma unroll 4
  for (int kc = 0; kc < 32; ++kc) {  // 32 chunks of K=32
    int kbase = kc * 32;
    short8 av = *(short8*)(ldsA + ((abase + (kbase + lhi * 8) * 2) ^ aswz));
    short8 bv0 = *(const short8*)(bpA + kbase);
    short8 bv1 = *(const short8*)(bpB + kbase);
    acc[0] = __builtin_amdgcn_mfma_f32_16x16x32_bf16(av, bv0, acc[0], 0, 0, 0);
    acc[1] = __builtin_amdgcn_mfma_f32_16x16x32_bf16(av, bv1, acc[1], 0, 0, 0);
  }

  // Epilogue 1: relu(h)+dot with aW2, reduce over 16-lane col group.
  float p0v[2], wv[2];
#pragma unroll
  for (int n = 0; n < 2; ++n) {
    int j = wn * 32 + n * 16 + llo;
    p0v[n] = p0[j];
    wv[n] = aW2[j];
  }
#pragma unroll
  for (int e = 0; e < 4; ++e) {
    float s = 0.f;
#pragma unroll
    for (int n = 0; n < 2; ++n) {
      float h = acc[n][e] + p0v[n];
      h = fmaxf(h, 0.f);
      s += h * wv[n];
    }
    s += __shfl_xor(s, 1);
    s += __shfl_xor(s, 2);
    s += __shfl_xor(s, 4);
    s += __shfl_xor(s, 8);
    if (llo == 0) part[wn * 32 + wm * 16 + lhi * 4 + e] = s;
  }
  __syncthreads();

  // Epilogue 2: combine 4 j-quarter partials, sigmoid, mask padded row.
  if (t < MR) {
    float pre = part[t] + part[32 + t] + part[64 + t] + part[96 + t] + ab2[0];
    int fr = 1 + bid * MR + t;
    float raw = 0.f;
    if (fr < NTOT) raw = 1.f / (1.f + __expf(-pre));
    part[128 + t] = raw;
  }
  __syncthreads();

  // Epilogue 3: agg[col] += sum_rows raw * f; each thread-half does 16 rows.
  float a0 = 0.f, a1 = 0.f, a2 = 0.f, a3 = 0.f;
  for (int lr = th * 16; lr < th * 16 + 16; ++lr) {
    float r = part[128 + lr];
    int off = (lr * 2048 + tc * 8) ^ ((lr & 7) << 4);
    uint2 pk = *(uint2*)(ldsA + off);
    a0 += r * bf2f(pk.x & 0xffffu);
    a1 += r * bf2f(pk.x >> 16);
    a2 += r * bf2f(pk.y & 0xffffu);
    a3 += r * bf2f(pk.y >> 16);
  }
  if (th == 1) {
    comb[tc * 4 + 0] = a0; comb[tc * 4 + 1] = a1;
    comb[tc * 4 + 2] = a2; comb[tc * 4 + 3] = a3;
  }
  __syncthreads();
  if (th == 0) {
    atomicAdd(agg + col + 0, a0 + comb[tc * 4 + 0]);
    atomicAdd(agg + col + 1, a1 + comb[tc * 4 + 1]);
    atomicAdd(agg + col + 2, a2 + comb[tc * 4 + 2]);
    atomicAdd(agg + col + 3, a3 + comb[tc * 4 + 3]);
  }
  if (t == 0) {
    float s = 0.f;
    for (int lr = 0; lr < MR; ++lr) s += part[128 + lr];
    atomicAdd(sacc + (bid & 63), s);
  }
}

// Kernel C1: c2 = [t, agg/s]; gate = sigmoid(gW.c2 + gb), u1 = relu(uW1.c2 + ub1).
__global__ __launch_bounds__(256) void kc1(const float* __restrict__ gW,
                                           const float* __restrict__ gb,
                                           const float* __restrict__ uW1,
                                           const float* __restrict__ ub1,
                                           float* __restrict__ ws) {
  __shared__ float c2[2048];
  __shared__ float sinv_sh;
  int t = threadIdx.x, bid = blockIdx.x;
  if (t == 0) {
    float s = 0.f;
    for (int i = 0; i < 64; ++i) s += ws[S_OFF + i];
    sinv_sh = (s > 0.f) ? 1.f / s : 1.f;
  }
  __syncthreads();
  float sinv = sinv_sh;
  for (int i = t; i < 2048; i += 256)
    c2[i] = (i < 1024) ? ws[T_OFF + i] : ws[AGG_OFF + i - 1024] * sinv;
  __syncthreads();
  int w = t >> 6, lane = t & 63;
  int isGate = bid < 256;
  int o = (isGate ? bid : bid - 256) * 4 + w;
  const float* W = isGate ? gW : uW1;
  float p = 0.f;
  for (int i = lane; i < 2048; i += 64) p += W[(size_t)o * 2048 + i] * c2[i];
  p += __shfl_xor(p, 1);
  p += __shfl_xor(p, 2);
  p += __shfl_xor(p, 4);
  p += __shfl_xor(p, 8);
  p += __shfl_xor(p, 16);
  p += __shfl_xor(p, 32);
  if (lane == 0) {
    float v = p + (isGate ? gb[o] : ub1[o]);
    v = isGate ? (1.f / (1.f + expf(-v))) : fmaxf(v, 0.f);
    ws[(isGate ? GATE_OFF : U1_OFF) + o] = v;
  }
}

// Kernel C2: upd = uW2.u1 + ub2; out[0] = t + gate * upd.
__global__ __launch_bounds__(256) void kc2(const float* __restrict__ uW2,
                                           const float* __restrict__ ub2,
                                           const float* __restrict__ ws,
                                           float* __restrict__ out) {
  __shared__ float u1[1024];
  int t = threadIdx.x, bid = blockIdx.x;
  for (int i = t; i < 1024; i += 256) u1[i] = ws[U1_OFF + i];
  __syncthreads();
  int w = t >> 6, lane = t & 63;
  int o = bid * 4 + w;
  float p = 0.f;
  for (int i = lane; i < 1024; i += 64) p += uW2[(size_t)o * 1024 + i] * u1[i];
  p += __shfl_xor(p, 1);
  p += __shfl_xor(p, 2);
  p += __shfl_xor(p, 4);
  p += __shfl_xor(p, 8);
  p += __shfl_xor(p, 16);
  p += __shfl_xor(p, 32);
  if (lane == 0) {
    float upd = p + ub2[o];
    out[o] = ws[T_OFF + o] + ws[GATE_OFF + o] * upd;
  }
}

extern "C" void kernel_launch(void* const* d_in, const int* in_sizes, int n_in,
                              void* d_out, int out_size, void* d_ws, size_t ws_size,
                              hipStream_t stream) {
  const float* features = (const float*)d_in[0];
  const int* depths = (const int*)d_in[1];
  const float* pos_emb = (const float*)d_in[2];
  const float* aW1 = (const float*)d_in[3];
  const float* ab1 = (const float*)d_in[4];
  const float* aW2 = (const float*)d_in[5];
  const float* ab2 = (const float*)d_in[6];
  const float* uW1 = (const float*)d_in[7];
  const float* ub1 = (const float*)d_in[8];
  const float* uW2 = (const float*)d_in[9];
  const float* ub2 = (const float*)d_in[10];
  const float* gW = (const float*)d_in[11];
  const float* gb = (const float*)d_in[12];
  float* out = (float*)d_out;
  float* ws = (float*)d_ws;
  unsigned short* w2 = (unsigned short*)(ws + W2_FOFF);

  hipLaunchKernelGGL(ka, dim3(1), dim3(256), 0, stream, features, depths, pos_emb, ws);
  hipLaunchKernelGGL(kaw, dim3(129), dim3(256), 0, stream, aW1, ab1, ws, w2);
  hipLaunchKernelGGL(kbig, dim3(1024), dim3(512), 0, stream, features, depths, pos_emb,
                     ws + P0_OFF, aW2, ab2, w2, out, ws + AGG_OFF, ws + S_OFF);
  hipLaunchKernelGGL(kc1, dim3(512), dim3(256), 0, stream, gW, gb, uW1, ub1, ws);
  hipLaunchKernelGGL(kc2, dim3(256), dim3(256), 0, stream, uW2, ub2, ws, out);
}

// Round 4
// 160.271 us; speedup vs baseline: 1.4443x; 1.3662x over previous
//
#include <hip/hip_runtime.h>

#define DNUM 1024
#define HIDN 128
#define NTOT 32768
#define MR 32
#define NBLK 1024

// workspace float offsets
#define T_OFF 0
#define P0_OFF 1024
#define S_OFF 1152
#define AGG_OFF 1216
#define GATE_OFF 2240
#define U1_OFF 3264
#define W2_FOFF 4288                       // bf16 W2: 128*1024 shorts = 65536 floats
#define AGGP_OFF (W2_FOFF + 65536)         // 69824: per-block agg partials, 1024*1024 f
#define SP_OFF (AGGP_OFF + NBLK * DNUM)    // per-block score sums, 1024 f
#define WS_NEED ((size_t)(SP_OFF + NBLK) * 4)

typedef __attribute__((ext_vector_type(8))) short short8;
typedef __attribute__((ext_vector_type(4))) float f32x4;

__device__ __forceinline__ unsigned short f2bf(float x) {
  unsigned int u = __builtin_bit_cast(unsigned int, x);
  u = u + 0x7fffu + ((u >> 16) & 1u);   // round-to-nearest-even
  return (unsigned short)(u >> 16);
}
__device__ __forceinline__ float bf2f(unsigned int bits16) {
  unsigned int u = bits16 << 16;
  return __builtin_bit_cast(float, u);
}

// Kernel A: target row t = features[0] + pos_emb[dep0]; zero s/agg accumulators.
__global__ __launch_bounds__(256) void ka(const float* __restrict__ features,
                                          const int* __restrict__ depths,
                                          const float* __restrict__ pos_emb,
                                          float* __restrict__ ws) {
  int t = threadIdx.x;
  int dep = depths[0];
  dep = dep < 0 ? 0 : (dep > 31 ? 31 : dep);
  float4 fv = *(const float4*)(features + t * 4);
  float4 pe = *(const float4*)(pos_emb + dep * DNUM + t * 4);
  float4 r;
  r.x = fv.x + pe.x; r.y = fv.y + pe.y; r.z = fv.z + pe.z; r.w = fv.w + pe.w;
  *(float4*)(ws + T_OFF + t * 4) = r;
  float4 z = make_float4(0.f, 0.f, 0.f, 0.f);
  *(float4*)(ws + AGG_OFF + t * 4) = z;
  if (t < 64) ws[S_OFF + t] = 0.f;
}

// Kernel AW: block 0 -> partial0[j] = ab1[j] + t . aW1[j, 0:1024] (2 thr/output);
// blocks 1..128 -> convert aW1[:, 1024:2048] to bf16 into ws.
__global__ __launch_bounds__(256) void kaw(const float* __restrict__ aW1,
                                           const float* __restrict__ ab1,
                                           float* __restrict__ ws,
                                           unsigned short* __restrict__ w2) {
  int t = threadIdx.x, bid = blockIdx.x;
  if (bid == 0) {
    __shared__ float ph[256];
    int j = t >> 1, h = t & 1;
    const float* wrow = aW1 + (size_t)j * (2 * DNUM) + h * 512;
    const float* tr = ws + T_OFF + h * 512;
    float p = 0.f;
    for (int k = 0; k < 512; k += 4) {
      float4 wv = *(const float4*)(wrow + k);
      float4 tv = *(const float4*)(tr + k);
      p += wv.x * tv.x + wv.y * tv.y + wv.z * tv.z + wv.w * tv.w;
    }
    ph[t] = p;
    __syncthreads();
    if (t < HIDN) ws[P0_OFF + t] = ab1[t] + ph[t * 2] + ph[t * 2 + 1];
    return;
  }
  int idx = ((bid - 1) * 256 + t) * 4;
  int j = idx >> 10, k = idx & 1023;
  float4 v = *(const float4*)(aW1 + (size_t)j * 2048 + 1024 + k);
  uint2 pk;
  pk.x = (unsigned int)f2bf(v.x) | ((unsigned int)f2bf(v.y) << 16);
  pk.y = (unsigned int)f2bf(v.z) | ((unsigned int)f2bf(v.w) << 16);
  *(uint2*)(w2 + idx) = pk;
}

// Kernel B (hot): per block, 32 path rows, 512 threads (8 waves).
// Stream f to d_out (NT stores), bf16 copy in LDS, barrier-free MFMA GEMM vs
// L2-resident w2, sigmoid scores, raw*f row-sum -> per-block partial (no atomics).
__global__ __launch_bounds__(512, 4) void kbig(
    const float* __restrict__ features, const int* __restrict__ depths,
    const float* __restrict__ pos_emb, const float* __restrict__ p0,
    const float* __restrict__ aW2, const float* __restrict__ ab2,
    const unsigned short* __restrict__ w2, float* __restrict__ out,
    float* __restrict__ agg, float* __restrict__ sacc,
    float* __restrict__ aggp, float* __restrict__ sp) {
  __shared__ __align__(16) unsigned char ldsA[MR * 2048];  // 64 KiB
  __shared__ int depsL[MR];
  __shared__ float part[160];       // [0..127] wave partials, [128..159] raw
  __shared__ float comb[1024];      // epilogue half-combine
  const int t = threadIdx.x;
  const int bid = blockIdx.x;
  const int lane = t & 63;
  const int w = t >> 6;
  const int llo = lane & 15;
  const int lhi = lane >> 4;
  const int tc = t & 255;           // column thread
  const int th = t >> 8;            // row half
  const int col = tc * 4;

  if (t < MR) {
    int fr = 1 + bid * MR + t;
    int dp = (fr < NTOT) ? depths[fr] : 0;
    dp = dp < 0 ? 0 : (dp > 31 ? 31 : dp);
    depsL[t] = dp;
  }
  __syncthreads();

  // Phase 1: build f rows, NT-write f32 to out, stage bf16 to LDS (XOR swizzle).
  for (int ii = 0; ii < 16; ++ii) {
    int i = ii * 2 + th;
    int fr = 1 + bid * MR + i;
    float4 f = make_float4(0.f, 0.f, 0.f, 0.f);
    if (fr < NTOT) {
      float4 fv = *(const float4*)(features + (size_t)fr * DNUM + col);
      float4 pe = *(const float4*)(pos_emb + depsL[i] * DNUM + col);
      f.x = fv.x + pe.x; f.y = fv.y + pe.y; f.z = fv.z + pe.z; f.w = fv.w + pe.w;
      f32x4 fe = {f.x, f.y, f.z, f.w};
      __builtin_nontemporal_store(fe, (f32x4*)(out + (size_t)fr * DNUM + col));
    }
    uint2 pk;
    pk.x = (unsigned int)f2bf(f.x) | ((unsigned int)f2bf(f.y) << 16);
    pk.y = (unsigned int)f2bf(f.z) | ((unsigned int)f2bf(f.w) << 16);
    int off = (i * 2048 + tc * 8) ^ ((i & 7) << 4);
    *(uint2*)(ldsA + off) = pk;
  }
  __syncthreads();

  // GEMM: wave (wm,wn) -> rows [wm*16,+16) x cols [wn*32,+32). No barriers.
  const int wm = w >> 2, wn = w & 3;
  f32x4 acc[2];
  acc[0] = (f32x4){0.f, 0.f, 0.f, 0.f};
  acc[1] = (f32x4){0.f, 0.f, 0.f, 0.f};
  const int arow = wm * 16 + llo;
  const int abase = arow * 2048;
  const int aswz = (arow & 7) << 4;
  const unsigned short* bpA = w2 + (size_t)(wn * 32 + llo) * DNUM + lhi * 8;
  const unsigned short* bpB = bpA + 16 * DNUM;

#pragma unroll 4
  for (int kc = 0; kc < 32; ++kc) {  // 32 chunks of K=32
    int kbase = kc * 32;
    short8 av = *(short8*)(ldsA + ((abase + (kbase + lhi * 8) * 2) ^ aswz));
    short8 bv0 = *(const short8*)(bpA + kbase);
    short8 bv1 = *(const short8*)(bpB + kbase);
    acc[0] = __builtin_amdgcn_mfma_f32_16x16x32_bf16(av, bv0, acc[0], 0, 0, 0);
    acc[1] = __builtin_amdgcn_mfma_f32_16x16x32_bf16(av, bv1, acc[1], 0, 0, 0);
  }

  // Epilogue 1: relu(h)+dot with aW2, reduce over 16-lane col group.
  float p0v[2], wv[2];
#pragma unroll
  for (int n = 0; n < 2; ++n) {
    int j = wn * 32 + n * 16 + llo;
    p0v[n] = p0[j];
    wv[n] = aW2[j];
  }
#pragma unroll
  for (int e = 0; e < 4; ++e) {
    float s = 0.f;
#pragma unroll
    for (int n = 0; n < 2; ++n) {
      float h = acc[n][e] + p0v[n];
      h = fmaxf(h, 0.f);
      s += h * wv[n];
    }
    s += __shfl_xor(s, 1);
    s += __shfl_xor(s, 2);
    s += __shfl_xor(s, 4);
    s += __shfl_xor(s, 8);
    if (llo == 0) part[wn * 32 + wm * 16 + lhi * 4 + e] = s;
  }
  __syncthreads();

  // Epilogue 2: combine 4 j-quarter partials, sigmoid, mask padded row.
  if (t < MR) {
    float pre = part[t] + part[32 + t] + part[64 + t] + part[96 + t] + ab2[0];
    int fr = 1 + bid * MR + t;
    float raw = 0.f;
    if (fr < NTOT) raw = 1.f / (1.f + __expf(-pre));
    part[128 + t] = raw;
  }
  __syncthreads();

  // Epilogue 3: partial agg row for this block; each thread-half does 16 rows.
  float a0 = 0.f, a1 = 0.f, a2 = 0.f, a3 = 0.f;
  for (int lr = th * 16; lr < th * 16 + 16; ++lr) {
    float r = part[128 + lr];
    int off = (lr * 2048 + tc * 8) ^ ((lr & 7) << 4);
    uint2 pk = *(uint2*)(ldsA + off);
    a0 += r * bf2f(pk.x & 0xffffu);
    a1 += r * bf2f(pk.x >> 16);
    a2 += r * bf2f(pk.y & 0xffffu);
    a3 += r * bf2f(pk.y >> 16);
  }
  if (th == 1) {
    comb[tc * 4 + 0] = a0; comb[tc * 4 + 1] = a1;
    comb[tc * 4 + 2] = a2; comb[tc * 4 + 3] = a3;
  }
  __syncthreads();
  if (th == 0) {
    float c0 = a0 + comb[tc * 4 + 0];
    float c1 = a1 + comb[tc * 4 + 1];
    float c2v = a2 + comb[tc * 4 + 2];
    float c3 = a3 + comb[tc * 4 + 3];
    if (aggp) {
      f32x4 v = {c0, c1, c2v, c3};
      *(f32x4*)(aggp + (size_t)bid * DNUM + col) = v;
    } else {
      atomicAdd(agg + col + 0, c0);
      atomicAdd(agg + col + 1, c1);
      atomicAdd(agg + col + 2, c2v);
      atomicAdd(agg + col + 3, c3);
    }
  }
  if (t == 0) {
    float s = 0.f;
    for (int lr = 0; lr < MR; ++lr) s += part[128 + lr];
    if (sp) sp[bid] = s;
    else atomicAdd(sacc + (bid & 63), s);
  }
}

// Kernel RED: blocks 0..255 -> one wave per column, agg[col] = sum_b aggp[b][col];
// block 256 -> ws[S_OFF] = sum_b sp[b].
__global__ __launch_bounds__(256) void kred(const float* __restrict__ aggp,
                                            const float* __restrict__ sp,
                                            float* __restrict__ ws) {
  int t = threadIdx.x, bid = blockIdx.x;
  if (bid < 256) {
    int w = t >> 6, lane = t & 63;
    int colIdx = bid * 4 + w;
    float s = 0.f;
#pragma unroll 4
    for (int k = 0; k < 16; ++k) {
      int r = lane + k * 64;
      s += aggp[(size_t)r * DNUM + colIdx];
    }
    s += __shfl_xor(s, 1);
    s += __shfl_xor(s, 2);
    s += __shfl_xor(s, 4);
    s += __shfl_xor(s, 8);
    s += __shfl_xor(s, 16);
    s += __shfl_xor(s, 32);
    if (lane == 0) ws[AGG_OFF + colIdx] = s;
  } else {
    __shared__ float red[256];
    float s = sp[t] + sp[t + 256] + sp[t + 512] + sp[t + 768];
    red[t] = s;
    __syncthreads();
    if (t < 64) {
      float v = red[t] + red[t + 64] + red[t + 128] + red[t + 192];
      v += __shfl_xor(v, 1);
      v += __shfl_xor(v, 2);
      v += __shfl_xor(v, 4);
      v += __shfl_xor(v, 8);
      v += __shfl_xor(v, 16);
      v += __shfl_xor(v, 32);
      if (t == 0) ws[S_OFF] = v;  // slots 1..63 stay 0 from ka
    }
  }
}

// Kernel C1: c2 = [t, agg/s]; gate = sigmoid(gW.c2 + gb), u1 = relu(uW1.c2 + ub1).
__global__ __launch_bounds__(256) void kc1(const float* __restrict__ gW,
                                           const float* __restrict__ gb,
                                           const float* __restrict__ uW1,
                                           const float* __restrict__ ub1,
                                           float* __restrict__ ws) {
  __shared__ float c2[2048];
  __shared__ float sinv_sh;
  int t = threadIdx.x, bid = blockIdx.x;
  if (t == 0) {
    float s = 0.f;
    for (int i = 0; i < 64; ++i) s += ws[S_OFF + i];
    sinv_sh = (s > 0.f) ? 1.f / s : 1.f;
  }
  __syncthreads();
  float sinv = sinv_sh;
  for (int i = t; i < 2048; i += 256)
    c2[i] = (i < 1024) ? ws[T_OFF + i] : ws[AGG_OFF + i - 1024] * sinv;
  __syncthreads();
  int w = t >> 6, lane = t & 63;
  int isGate = bid < 256;
  int o = (isGate ? bid : bid - 256) * 4 + w;
  const float* W = isGate ? gW : uW1;
  float p = 0.f;
  for (int i = lane; i < 2048; i += 64) p += W[(size_t)o * 2048 + i] * c2[i];
  p += __shfl_xor(p, 1);
  p += __shfl_xor(p, 2);
  p += __shfl_xor(p, 4);
  p += __shfl_xor(p, 8);
  p += __shfl_xor(p, 16);
  p += __shfl_xor(p, 32);
  if (lane == 0) {
    float v = p + (isGate ? gb[o] : ub1[o]);
    v = isGate ? (1.f / (1.f + expf(-v))) : fmaxf(v, 0.f);
    ws[(isGate ? GATE_OFF : U1_OFF) + o] = v;
  }
}

// Kernel C2: upd = uW2.u1 + ub2; out[0] = t + gate * upd.
__global__ __launch_bounds__(256) void kc2(const float* __restrict__ uW2,
                                           const float* __restrict__ ub2,
                                           const float* __restrict__ ws,
                                           float* __restrict__ out) {
  __shared__ float u1[1024];
  int t = threadIdx.x, bid = blockIdx.x;
  for (int i = t; i < 1024; i += 256) u1[i] = ws[U1_OFF + i];
  __syncthreads();
  int w = t >> 6, lane = t & 63;
  int o = bid * 4 + w;
  float p = 0.f;
  for (int i = lane; i < 1024; i += 64) p += uW2[(size_t)o * 1024 + i] * u1[i];
  p += __shfl_xor(p, 1);
  p += __shfl_xor(p, 2);
  p += __shfl_xor(p, 4);
  p += __shfl_xor(p, 8);
  p += __shfl_xor(p, 16);
  p += __shfl_xor(p, 32);
  if (lane == 0) {
    float upd = p + ub2[o];
    out[o] = ws[T_OFF + o] + ws[GATE_OFF + o] * upd;
  }
}

extern "C" void kernel_launch(void* const* d_in, const int* in_sizes, int n_in,
                              void* d_out, int out_size, void* d_ws, size_t ws_size,
                              hipStream_t stream) {
  const float* features = (const float*)d_in[0];
  const int* depths = (const int*)d_in[1];
  const float* pos_emb = (const float*)d_in[2];
  const float* aW1 = (const float*)d_in[3];
  const float* ab1 = (const float*)d_in[4];
  const float* aW2 = (const float*)d_in[5];
  const float* ab2 = (const float*)d_in[6];
  const float* uW1 = (const float*)d_in[7];
  const float* ub1 = (const float*)d_in[8];
  const float* uW2 = (const float*)d_in[9];
  const float* ub2 = (const float*)d_in[10];
  const float* gW = (const float*)d_in[11];
  const float* gb = (const float*)d_in[12];
  float* out = (float*)d_out;
  float* ws = (float*)d_ws;
  unsigned short* w2 = (unsigned short*)(ws + W2_FOFF);
  bool useP = ws_size >= WS_NEED;
  float* aggp = useP ? (ws + AGGP_OFF) : nullptr;
  float* sp = useP ? (ws + SP_OFF) : nullptr;

  hipLaunchKernelGGL(ka, dim3(1), dim3(256), 0, stream, features, depths, pos_emb, ws);
  hipLaunchKernelGGL(kaw, dim3(129), dim3(256), 0, stream, aW1, ab1, ws, w2);
  hipLaunchKernelGGL(kbig, dim3(NBLK), dim3(512), 0, stream, features, depths, pos_emb,
                     ws + P0_OFF, aW2, ab2, w2, out, ws + AGG_OFF, ws + S_OFF, aggp, sp);
  if (useP)
    hipLaunchKernelGGL(kred, dim3(257), dim3(256), 0, stream, aggp, sp, ws);
  hipLaunchKernelGGL(kc1, dim3(512), dim3(256), 0, stream, gW, gb, uW1, ub1, ws);
  hipLaunchKernelGGL(kc2, dim3(256), dim3(256), 0, stream, uW2, ub2, ws, out);
}